// Round 6
// baseline (225.615 us; speedup 1.0000x reference)
//
#include <hip/hip_runtime.h>
#include <float.h>

#define HW    4096      // H*W
#define NC    64        // channels / latent dim
#define NK    1024      // codebook entries
#define NB    32        // batch
#define NPIX  (NB*HW)   // 131072 pixels
#define TOTAL (NPIX*NC) // 8388608 output elements of z_q
#define PPB   128       // pixels per block (32 per wave, 2 MFMA B-sets)

// bf16 hi/lo split score error bound ~1.4e-3 worst case; MARGIN 8e-3 gives
// >4x safety (validated: absmax 0 in rounds 4-5). gap2<MARGIN -> exact fp64
// top-2 compare; gap3<MARGIN (rare) -> cooperative exact fp64 full rescan.
#define MARGIN 8e-3f

typedef __attribute__((ext_vector_type(8))) short short8;   // 8 bf16 (4 VGPRs)
typedef __attribute__((ext_vector_type(4))) float floatx4;  // MFMA acc

__device__ __forceinline__ unsigned short f2bf(float f) {   // fp32 -> bf16 RNE
    unsigned u = __float_as_uint(f);
    u += 0x7FFFu + ((u >> 16) & 1u);
    return (unsigned short)(u >> 16);
}
__device__ __forceinline__ float bf2f(unsigned short h) {
    return __uint_as_float(((unsigned)h) << 16);
}

// top-3 insert using v_med3_f32 (10 VALU incl. score-form, was 13):
//   b2' = med3(s, b1, b2)   (second-smallest of {b1,b2,s}, since b1<=b2)
//   b3' = med3(s, b2, b3)   (third-smallest of {b1,b2,b3,s})
// In-sweep k is strictly increasing; s<b1 strict keeps the first min.
// lt2 uses <= so an exact tie with b1/b2 still lands index k in i2; any
// >=3-way fp32 tie collapses gap3 to 0 -> full rescan, so ties stay safe.
__device__ __forceinline__ void ins3f(float& b1, int& i1, float& b2, int& i2,
                                      float& b3, float s, int k) {
    bool lt1 = s < b1;
    bool lt2 = s <= b2;
    float nb3 = __builtin_amdgcn_fmed3f(s, b2, b3);
    float nb2 = __builtin_amdgcn_fmed3f(s, b1, b2);
    i2 = lt1 ? i1 : (lt2 ? k : i2);
    i1 = lt1 ? k : i1;
    b1 = fminf(s, b1);
    b2 = nb2;
    b3 = nb3;
}
// tie-aware version for cross-lane merge (lower index wins on equal score)
__device__ __forceinline__ void ins3t(float& b1, int& i1, float& b2, int& i2,
                                      float& b3, float s, int k) {
    bool lt1 = (s < b1) || (s == b1 && k < i1);
    bool lt2 = (s < b2) || (s == b2 && k < i2);
    float nb3 = __builtin_amdgcn_fmed3f(s, b2, b3);
    float nb2 = lt1 ? b1 : (lt2 ? s : b2);
    i2 = lt1 ? i1 : (lt2 ? k : i2);
    i1 = lt1 ? k : i1;
    b1 = lt1 ? s : b1;
    b2 = nb2;
    b3 = nb3;
}

// Prologue: cnorm (fp64-accurate), bf16 hi/lo codebook splits, zero loss.
// 16 blocks x 64 threads so it doesn't serialize on 4 CUs.
__global__ void vq_prep_kernel(const float* __restrict__ cb,
                               float* __restrict__ cnorm,
                               unsigned short* __restrict__ cb_hi,
                               unsigned short* __restrict__ cb_lo,
                               float* __restrict__ loss_out) {
    int k = blockIdx.x * 64 + threadIdx.x;
    if (k == 0) loss_out[0] = 0.0f;
    if (k < NK) {
        const float4* r4 = (const float4*)(cb + (size_t)k * NC);
        double s = 0.0;
        #pragma unroll
        for (int j = 0; j < 16; ++j) {
            float4 v = r4[j];
            const float fv[4] = {v.x, v.y, v.z, v.w};
            #pragma unroll
            for (int t = 0; t < 4; ++t) {
                float f = fv[t];
                unsigned short h = f2bf(f);
                unsigned short l = f2bf(f - bf2f(h));
                cb_hi[k * NC + 4 * j + t] = h;
                cb_lo[k * NC + 4 * j + t] = l;
                double dv = (double)f;
                s = fma(dv, dv, s);
            }
        }
        cnorm[k] = (float)s;
    }
}

// Main: block = 256 threads / 4 waves / 128 pixels (32 per wave, 2 B-sets).
// LDS ~40 KB -> 4 blocks/CU -> 4 waves/SIMD: TLP hides the per-tile L2
// latency of the A-fragment loads without fragile register prefetch.
__global__ __launch_bounds__(256, 4) void vq_mfma_kernel(
        const float* __restrict__ z,
        const float* __restrict__ cb,
        const unsigned short* __restrict__ cb_hi,
        const unsigned short* __restrict__ cb_lo,
        const float* __restrict__ cnorm,
        float* __restrict__ zq,
        float* __restrict__ loss_out) {
    __shared__ unsigned short zh[64][PPB];   // [ch][px] bf16-hi of z (16 KB)
    __shared__ unsigned short zl[64][PPB];   // bf16-lo (16 KB)
    __shared__ alignas(16) float cn_lds[NK]; // 4 KB; aliased by rescan scratch
    __shared__ float rb1[PPB], rb2[PPB], rb3[PPB];
    __shared__ int   ri1[PPB], ri2[PPB];
    __shared__ int   finidx[PPB];
    __shared__ int   flags[PPB];
    __shared__ float redf[4];

    const int tid = threadIdx.x;
    const int g0  = blockIdx.x * PPB;        // first pixel of block
    const int bb  = g0 >> 12;                // batch (128 | 4096 -> uniform)
    const int pp0 = g0 & 4095;
    const float* zbase = z  + (size_t)bb * (NC * HW) + pp0;
    float*      zqbase = zq + (size_t)bb * (NC * HW) + pp0;

    // ---- stage cnorm -> LDS ----
    ((float4*)cn_lds)[tid] = ((const float4*)cnorm)[tid];

    // ---- stage z -> bf16 hi/lo in LDS, layout [ch][px] ----
    {
        const int px4 = (tid & 31) * 4;      // 0..124
        const int c0  = tid >> 5;            // 0..7
        #pragma unroll
        for (int it = 0; it < 8; ++it) {
            const int c = it * 8 + c0;
            float4 v = *(const float4*)(zbase + (size_t)c * HW + px4);
            unsigned short h0 = f2bf(v.x), h1 = f2bf(v.y),
                           h2 = f2bf(v.z), h3 = f2bf(v.w);
            unsigned short l0 = f2bf(v.x - bf2f(h0)), l1 = f2bf(v.y - bf2f(h1)),
                           l2 = f2bf(v.z - bf2f(h2)), l3 = f2bf(v.w - bf2f(h3));
            uint2 ph = make_uint2((unsigned)h0 | ((unsigned)h1 << 16),
                                  (unsigned)h2 | ((unsigned)h3 << 16));
            uint2 pl = make_uint2((unsigned)l0 | ((unsigned)l1 << 16),
                                  (unsigned)l2 | ((unsigned)l3 << 16));
            *(uint2*)&zh[c][px4] = ph;
            *(uint2*)&zl[c][px4] = pl;
        }
    }
    __syncthreads();

    // ---- hoisted B fragments: 2 pixel sets per wave ----
    const int lane = tid & 63;
    const int w    = tid >> 6;
    const int q    = lane >> 4;
    const int pcol = lane & 15;

    short8 Bh0[2], Bh1[2], Bl0[2], Bl1[2];
    #pragma unroll
    for (int j = 0; j < 2; ++j) {
        const int px = w * 32 + j * 16 + pcol;   // this lane's pixel, set j
        #pragma unroll
        for (int t = 0; t < 8; ++t) {
            Bh0[j][t] = (short)zh[q * 8 + t][px];
            Bh1[j][t] = (short)zh[32 + q * 8 + t][px];
            Bl0[j][t] = (short)zl[q * 8 + t][px];
            Bl1[j][t] = (short)zl[32 + q * 8 + t][px];
        }
    }

    // ---- sweep 64 code tiles ----
    const short8* cbh8 = (const short8*)cb_hi;
    const short8* cbl8 = (const short8*)cb_lo;

    float B1[2], B2[2], B3[2];
    int   I1[2], I2[2];
    #pragma unroll
    for (int j = 0; j < 2; ++j) {
        B1[j] = FLT_MAX; B2[j] = FLT_MAX; B3[j] = FLT_MAX;
        I1[j] = 0; I2[j] = 0;
    }

    #pragma unroll 2
    for (int tile = 0; tile < 64; ++tile) {
        const int r = tile * 16 + pcol;          // A row for this lane
        short8 ah0 = cbh8[r * 8 + q];
        short8 ah1 = cbh8[r * 8 + 4 + q];
        short8 al0 = cbl8[r * 8 + q];
        short8 al1 = cbl8[r * 8 + 4 + q];

        const float4 cn4 = *(const float4*)&cn_lds[tile * 16 + q * 4];
        const int kb = tile * 16 + q * 4;
        #pragma unroll
        for (int j = 0; j < 2; ++j) {
            floatx4 a0 = {0.f, 0.f, 0.f, 0.f};
            floatx4 a1 = {0.f, 0.f, 0.f, 0.f};
            // dot = zh*eh + zh*el + zl*eh (zl*el dropped, ~2^-18 relative)
            a0 = __builtin_amdgcn_mfma_f32_16x16x32_bf16(ah0, Bh0[j], a0, 0, 0, 0);
            a1 = __builtin_amdgcn_mfma_f32_16x16x32_bf16(ah1, Bh1[j], a1, 0, 0, 0);
            a0 = __builtin_amdgcn_mfma_f32_16x16x32_bf16(ah0, Bl0[j], a0, 0, 0, 0);
            a1 = __builtin_amdgcn_mfma_f32_16x16x32_bf16(ah1, Bl1[j], a1, 0, 0, 0);
            a0 = __builtin_amdgcn_mfma_f32_16x16x32_bf16(al0, Bh0[j], a0, 0, 0, 0);
            a1 = __builtin_amdgcn_mfma_f32_16x16x32_bf16(al1, Bh1[j], a1, 0, 0, 0);

            // C/D layout: code row = q*4+reg, pixel col = lane&15 (verified)
            float s0 = fmaf(-2.f, a0[0] + a1[0], cn4.x);
            float s1 = fmaf(-2.f, a0[1] + a1[1], cn4.y);
            float s2 = fmaf(-2.f, a0[2] + a1[2], cn4.z);
            float s3 = fmaf(-2.f, a0[3] + a1[3], cn4.w);
            ins3f(B1[j], I1[j], B2[j], I2[j], B3[j], s0, kb + 0);
            ins3f(B1[j], I1[j], B2[j], I2[j], B3[j], s1, kb + 1);
            ins3f(B1[j], I1[j], B2[j], I2[j], B3[j], s2, kb + 2);
            ins3f(B1[j], I1[j], B2[j], I2[j], B3[j], s3, kb + 3);
        }
    }

    // ---- merge top-3 across the 4 lanes sharing each pixel (xor 16,32) ----
    #pragma unroll
    for (int j = 0; j < 2; ++j) {
        float b1v = B1[j], b2v = B2[j], b3v = B3[j];
        int i1 = I1[j], i2 = I2[j];
        #pragma unroll
        for (int d = 16; d <= 32; d <<= 1) {
            float ob1 = __shfl_xor(b1v, d);
            int   oi1 = __shfl_xor(i1, d);
            float ob2 = __shfl_xor(b2v, d);
            int   oi2 = __shfl_xor(i2, d);
            float ob3 = __shfl_xor(b3v, d);
            ins3t(b1v, i1, b2v, i2, b3v, ob1, oi1);
            ins3t(b1v, i1, b2v, i2, b3v, ob2, oi2);
            b3v = fminf(b3v, ob3);
        }
        if (q == 0) {
            const int px = w * 32 + j * 16 + pcol;
            rb1[px] = b1v; rb2[px] = b2v; rb3[px] = b3v;
            ri1[px] = i1;  ri2[px] = i2;
        }
    }
    __syncthreads();

    // ---- per-pixel decision (1 thread per pixel) ----
    int flag = 0;
    if (tid < PPB) {
        const int p = tid;
        int fi = ri1[p];
        const float g3 = rb3[p] - rb1[p];
        const float g2 = rb2[p] - rb1[p];
        if (g3 < MARGIN) {
            flag = 1;                        // needs cooperative full rescan
        } else if (g2 < MARGIN) {
            // true argmin provably in {ri1, ri2}: exact fp64 compare
            const float* zp = zbase + p;
            const int ia = fi, ib = ri2[p];
            const float* ra  = cb + (size_t)ia * NC;
            const float* rbp = cb + (size_t)ib * NC;
            double sa = 0.0, sb = 0.0;
            for (int c = 0; c < NC; ++c) {
                double zv = (double)zp[(size_t)c * HW];
                double ta = zv - (double)ra[c];
                double tb = zv - (double)rbp[c];
                sa = fma(ta, ta, sa);
                sb = fma(tb, tb, sb);
            }
            if (sb < sa || (sb == sa && ib < ia)) fi = ib;
        }
        finidx[p] = fi;
        flags[p]  = flag;
    }
    const int nflag = __syncthreads_count(flag);

    // ---- rare cooperative exact rescan (scratch aliases cn_lds) ----
    if (nflag > 0) {
        double* red_s = reinterpret_cast<double*>(cn_lds);       // 2 KB
        int*    red_i = reinterpret_cast<int*>(cn_lds + 512);    // 1 KB
        for (int p = 0; p < PPB; ++p) {
            if (flags[p]) {
                const float* zp = zbase + p;
                double bd = 1.0e300; int bi = 0;
                #pragma unroll 1
                for (int r = 0; r < 4; ++r) {
                    const int k = tid * 4 + r;
                    const float* rowp = cb + (size_t)k * NC;
                    double s = 0.0;
                    for (int c = 0; c < NC; ++c) {
                        double t = (double)zp[(size_t)c * HW] - (double)rowp[c];
                        s = fma(t, t, s);
                    }
                    if (s < bd) { bd = s; bi = k; }  // k increasing: first min
                }
                red_s[tid] = bd; red_i[tid] = bi;
                __syncthreads();
                if (tid < 64) {
                    double m = red_s[tid]; int mi = red_i[tid];
                    #pragma unroll
                    for (int t = 1; t < 4; ++t) {
                        double om = red_s[tid + 64 * t];
                        int    oi = red_i[tid + 64 * t];
                        if (om < m || (om == m && oi < mi)) { m = om; mi = oi; }
                    }
                    #pragma unroll
                    for (int off = 32; off > 0; off >>= 1) {
                        double om = __shfl_down(m, off);
                        int    oi = __shfl_down(mi, off);
                        if (om < m || (om == m && oi < mi)) { m = om; mi = oi; }
                    }
                    if (tid == 0) finidx[p] = mi;
                }
                __syncthreads();
            }
        }
        __syncthreads();
    }

    // ---- epilogue: gather exact fp32 code row -> z_q, loss SSE ----
    // 2 threads per pixel, 32 channels each.
    {
        const int p  = tid & (PPB - 1);
        const int qq = tid >> 7;             // 0..1
        const int fi = finidx[p];
        const float4* crow4 = (const float4*)(cb + (size_t)fi * NC) + qq * 8;
        float sse = 0.f;
        #pragma unroll
        for (int j = 0; j < 8; ++j) {
            const float4 qv = crow4[j];
            const size_t c0 = (size_t)(qq * 32 + 4 * j) * HW + p;
            const float z0 = zbase[c0];
            const float z1 = zbase[c0 + HW];
            const float z2 = zbase[c0 + 2 * (size_t)HW];
            const float z3 = zbase[c0 + 3 * (size_t)HW];
            zqbase[c0]                  = qv.x;   // coalesced across threads
            zqbase[c0 + HW]             = qv.y;
            zqbase[c0 + 2 * (size_t)HW] = qv.z;
            zqbase[c0 + 3 * (size_t)HW] = qv.w;
            float t0 = qv.x - z0, t1 = qv.y - z1, t2 = qv.z - z2, t3 = qv.w - z3;
            sse = fmaf(t0, t0, sse);
            sse = fmaf(t1, t1, sse);
            sse = fmaf(t2, t2, sse);
            sse = fmaf(t3, t3, sse);
        }
        #pragma unroll
        for (int off = 32; off > 0; off >>= 1) sse += __shfl_down(sse, off);
        if ((tid & 63) == 0) redf[tid >> 6] = sse;
        __syncthreads();
        if (tid == 0)
            atomicAdd(loss_out, (redf[0] + redf[1] + redf[2] + redf[3]) *
                                (1.25f / (float)TOTAL));
    }
}

extern "C" void kernel_launch(void* const* d_in, const int* in_sizes, int n_in,
                              void* d_out, int out_size, void* d_ws, size_t ws_size,
                              hipStream_t stream) {
    const float* z  = (const float*)d_in[0];   // [32, 64, 64, 64] fp32
    const float* cb = (const float*)d_in[1];   // [1024, 64] fp32
    float* out      = (float*)d_out;           // z_q ++ loss
    float* zqp      = out;
    float* loss     = out + TOTAL;

    // ws: cnorm fp32[1024] | cb_hi bf16[1024*64] | cb_lo bf16[1024*64]
    float* cnorm          = (float*)d_ws;
    unsigned short* cb_hi = (unsigned short*)((char*)d_ws + 4096);
    unsigned short* cb_lo = (unsigned short*)((char*)d_ws + 4096 + NK * NC * 2);

    vq_prep_kernel<<<16, 64, 0, stream>>>(cb, cnorm, cb_hi, cb_lo, loss);
    vq_mfma_kernel<<<NPIX / PPB, 256, 0, stream>>>(z, cb, cb_hi, cb_lo, cnorm,
                                                   zqp, loss);
}

// Round 7
// 177.551 us; speedup vs baseline: 1.2707x; 1.2707x over previous
//
#include <hip/hip_runtime.h>
#include <float.h>

#define HW    4096      // H*W
#define NC    64        // channels / latent dim
#define NK    1024      // codebook entries
#define NB    32        // batch
#define NPIX  (NB*HW)   // 131072 pixels
#define TOTAL (NPIX*NC) // 8388608 output elements of z_q
#define PPB   128       // pixels per block (32 per wave, 2 MFMA B-sets)

// bf16 hi/lo split score error bound ~1.4e-3 worst case; MARGIN 8e-3 gives
// >4x safety (validated rounds 4-6, absmax 0). gap2<MARGIN (incl. any exact
// fp32 tie) -> cooperative exact fp64 full rescan (~0.13%/pixel).
#define MARGIN 8e-3f

typedef __attribute__((ext_vector_type(8))) short short8;   // 8 bf16 (4 VGPRs)
typedef __attribute__((ext_vector_type(4))) float floatx4;  // MFMA acc

__device__ __forceinline__ unsigned short f2bf(float f) {   // fp32 -> bf16 RNE
    unsigned u = __float_as_uint(f);
    u += 0x7FFFu + ((u >> 16) & 1u);
    return (unsigned short)(u >> 16);
}
__device__ __forceinline__ float bf2f(unsigned short h) {
    return __uint_as_float(((unsigned)h) << 16);
}

// Prologue: cnorm (fp64-accurate), bf16 hi/lo codebook splits, zero loss.
__global__ void vq_prep_kernel(const float* __restrict__ cb,
                               float* __restrict__ cnorm,
                               unsigned short* __restrict__ cb_hi,
                               unsigned short* __restrict__ cb_lo,
                               float* __restrict__ loss_out) {
    int k = blockIdx.x * 64 + threadIdx.x;
    if (k == 0) loss_out[0] = 0.0f;
    if (k < NK) {
        const float4* r4 = (const float4*)(cb + (size_t)k * NC);
        double s = 0.0;
        #pragma unroll
        for (int j = 0; j < 16; ++j) {
            float4 v = r4[j];
            const float fv[4] = {v.x, v.y, v.z, v.w};
            #pragma unroll
            for (int t = 0; t < 4; ++t) {
                float f = fv[t];
                unsigned short h = f2bf(f);
                unsigned short l = f2bf(f - bf2f(h));
                cb_hi[k * NC + 4 * j + t] = h;
                cb_lo[k * NC + 4 * j + t] = l;
                double dv = (double)f;
                s = fma(dv, dv, s);
            }
        }
        cnorm[k] = (float)s;
    }
}

// Main: block = 256 threads / 4 waves / 128 pixels. A-tiles (4 KB = hi+lo of
// 16 codes) are staged ONCE per block into double-buffered LDS (aliased onto
// the dead z-staging space), so waves read fragments via ds_read_b128 instead
// of 4 redundant global loads each. cnorm rides the MFMA C operand; -2 is
// folded into the z split -> score = a0[i]+a1[i].
__global__ __launch_bounds__(256, 4) void vq_mfma_kernel(
        const float* __restrict__ z,
        const float* __restrict__ cb,
        const unsigned short* __restrict__ cb_hi,
        const unsigned short* __restrict__ cb_lo,
        const float* __restrict__ cnorm,
        float* __restrict__ zq,
        float* __restrict__ loss_out) {
    // 32 KB region: phase 1 = zh/zl staging, phase 2 = A-tile double buffer.
    __shared__ alignas(16) char smem[32768];
    __shared__ alignas(16) float cn_lds[NK];   // 4 KB; rescan scratch aliases
    __shared__ int   finidx[PPB];
    __shared__ int   flags[PPB];
    __shared__ float redf[4];

    const int tid = threadIdx.x;
    const int g0  = blockIdx.x * PPB;
    const int bb  = g0 >> 12;
    const int pp0 = g0 & 4095;
    const float* zbase = z  + (size_t)bb * (NC * HW) + pp0;
    float*      zqbase = zq + (size_t)bb * (NC * HW) + pp0;

    // ---- stage cnorm -> LDS ----
    ((float4*)cn_lds)[tid] = ((const float4*)cnorm)[tid];

    // ---- phase 1: z -> bf16 hi/lo of (-2*z), layout [ch][px] ----
    unsigned short (*zh)[PPB] = (unsigned short(*)[PPB])smem;
    unsigned short (*zl)[PPB] = (unsigned short(*)[PPB])(smem + 16384);
    {
        const int px4 = (tid & 31) * 4;
        const int c0  = tid >> 5;
        #pragma unroll
        for (int it = 0; it < 8; ++it) {
            const int c = it * 8 + c0;
            float4 v = *(const float4*)(zbase + (size_t)c * HW + px4);
            v.x *= -2.0f; v.y *= -2.0f; v.z *= -2.0f; v.w *= -2.0f;
            unsigned short h0 = f2bf(v.x), h1 = f2bf(v.y),
                           h2 = f2bf(v.z), h3 = f2bf(v.w);
            unsigned short l0 = f2bf(v.x - bf2f(h0)), l1 = f2bf(v.y - bf2f(h1)),
                           l2 = f2bf(v.z - bf2f(h2)), l3 = f2bf(v.w - bf2f(h3));
            uint2 ph = make_uint2((unsigned)h0 | ((unsigned)h1 << 16),
                                  (unsigned)h2 | ((unsigned)h3 << 16));
            uint2 pl = make_uint2((unsigned)l0 | ((unsigned)l1 << 16),
                                  (unsigned)l2 | ((unsigned)l3 << 16));
            *(uint2*)&zh[c][px4] = ph;
            *(uint2*)&zl[c][px4] = pl;
        }
    }
    __syncthreads();

    // ---- hoisted B fragments (z side), 2 pixel sets per wave ----
    const int lane = tid & 63;
    const int w    = tid >> 6;
    const int q    = lane >> 4;
    const int pcol = lane & 15;

    short8 Bh0[2], Bh1[2], Bl0[2], Bl1[2];
    #pragma unroll
    for (int j = 0; j < 2; ++j) {
        const int px = w * 32 + j * 16 + pcol;
        #pragma unroll
        for (int t = 0; t < 8; ++t) {
            Bh0[j][t] = (short)zh[q * 8 + t][px];
            Bh1[j][t] = (short)zh[32 + q * 8 + t][px];
            Bl0[j][t] = (short)zl[q * 8 + t][px];
            Bl1[j][t] = (short)zl[32 + q * 8 + t][px];
        }
    }
    __syncthreads();   // zh/zl dead; smem becomes the A-tile double buffer

    // ---- phase 2: sweep 64 tiles, A staged via LDS double buffer ----
    // abuf layout (uint4 units): [buf(2)][part(2)][chunk(8)][row(16)]
    uint4* abuf = (uint4*)smem;
    const int spart = tid >> 7;            // 0 = hi, 1 = lo
    const int sidx  = tid & 127;           // row*8 + chunk of the 2 KB part
    const int ldst  = spart * 128 + (sidx & 7) * 16 + (sidx >> 3);
    const char* gsrc = (spart == 0 ? (const char*)cb_hi : (const char*)cb_lo)
                       + (size_t)sidx * 16;

    uint4 sreg = *(const uint4*)(gsrc);            // tile 0
    abuf[ldst] = sreg;                             // -> buf 0
    sreg = *(const uint4*)(gsrc + 2048);           // tile 1
    __syncthreads();                               // buf0 visible

    float B1[2] = {FLT_MAX, FLT_MAX}, B2[2] = {FLT_MAX, FLT_MAX};
    int   I1[2] = {0, 0};

    #pragma unroll 2
    for (int tile = 0; tile < 64; ++tile) {
        if (tile < 63) abuf[((tile + 1) & 1) * 256 + ldst] = sreg;
        if (tile < 62) sreg = *(const uint4*)(gsrc + (size_t)(tile + 2) * 2048);

        const short8* A = (const short8*)smem + (tile & 1) * 256;
        short8 ah0 = A[q * 16 + pcol];             // part0 chunk q   row pcol
        short8 ah1 = A[(4 + q) * 16 + pcol];       // part0 chunk 4+q
        short8 al0 = A[128 + q * 16 + pcol];       // part1 chunk q
        short8 al1 = A[128 + (4 + q) * 16 + pcol]; // part1 chunk 4+q

        const floatx4 cn4 = *(const floatx4*)&cn_lds[tile * 16 + q * 4];
        const int kb = tile * 16 + q * 4;
        #pragma unroll
        for (int j = 0; j < 2; ++j) {
            // score = cn + (-2z).e :  e_hi*z_hi + e_hi*z_lo + e_lo*z_hi
            floatx4 a0 = __builtin_amdgcn_mfma_f32_16x16x32_bf16(ah0, Bh0[j], cn4, 0, 0, 0);
            floatx4 a1 = {0.f, 0.f, 0.f, 0.f};
            a1 = __builtin_amdgcn_mfma_f32_16x16x32_bf16(ah1, Bh1[j], a1, 0, 0, 0);
            a0 = __builtin_amdgcn_mfma_f32_16x16x32_bf16(ah0, Bl0[j], a0, 0, 0, 0);
            a1 = __builtin_amdgcn_mfma_f32_16x16x32_bf16(ah1, Bl1[j], a1, 0, 0, 0);
            a0 = __builtin_amdgcn_mfma_f32_16x16x32_bf16(al0, Bh0[j], a0, 0, 0, 0);
            a1 = __builtin_amdgcn_mfma_f32_16x16x32_bf16(al1, Bh1[j], a1, 0, 0, 0);

            // C/D layout: code row = q*4+reg, pixel col = lane&15 (verified)
            #pragma unroll
            for (int i = 0; i < 4; ++i) {
                float s = a0[i] + a1[i];
                bool lt = s < B1[j];                 // strict: first min wins
                I1[j] = lt ? (kb + i) : I1[j];
                B2[j] = __builtin_amdgcn_fmed3f(s, B1[j], B2[j]);
                B1[j] = fminf(s, B1[j]);
            }
        }
        __syncthreads();   // next buffer fully written before anyone reads it
    }

    // ---- merge top-2 across the 4 lanes sharing each pixel (xor 16,32) ----
    #pragma unroll
    for (int j = 0; j < 2; ++j) {
        float b1 = B1[j], b2 = B2[j];
        int i1 = I1[j];
        #pragma unroll
        for (int d = 16; d <= 32; d <<= 1) {
            float ob1 = __shfl_xor(b1, d);
            float ob2 = __shfl_xor(b2, d);
            int   oi1 = __shfl_xor(i1, d);
            // second-smallest of {b1,b2,ob1,ob2}; equal b1s -> gap 0 -> rescan
            float nb2 = fminf(fmaxf(b1, ob1), fminf(b2, ob2));
            bool lt = (ob1 < b1) || (ob1 == b1 && oi1 < i1);
            b1 = lt ? ob1 : b1;
            i1 = lt ? oi1 : i1;
            b2 = nb2;
        }
        if (q == 0) {
            const int px = w * 32 + j * 16 + pcol;
            finidx[px] = i1;
            flags[px]  = (b2 - b1 < MARGIN) ? 1 : 0;
        }
    }
    int myflag = 0;
    __syncthreads();
    if (tid < PPB) myflag = flags[tid];
    const int nflag = __syncthreads_count(myflag);

    // ---- rare cooperative exact fp64 rescan (scratch aliases cn_lds) ----
    if (nflag > 0) {
        double* red_s = reinterpret_cast<double*>(cn_lds);       // 2 KB
        int*    red_i = reinterpret_cast<int*>(cn_lds + 512);    // 1 KB
        for (int p = 0; p < PPB; ++p) {
            if (flags[p]) {
                const float* zp = zbase + p;
                double bd = 1.0e300; int bi = 0;
                #pragma unroll 1
                for (int r = 0; r < 4; ++r) {
                    const int k = tid * 4 + r;
                    const float* rowp = cb + (size_t)k * NC;
                    double s = 0.0;
                    for (int c = 0; c < NC; ++c) {
                        double t = (double)zp[(size_t)c * HW] - (double)rowp[c];
                        s = fma(t, t, s);
                    }
                    if (s < bd) { bd = s; bi = k; }  // k increasing: first min
                }
                red_s[tid] = bd; red_i[tid] = bi;
                __syncthreads();
                if (tid < 64) {
                    double m = red_s[tid]; int mi = red_i[tid];
                    #pragma unroll
                    for (int t = 1; t < 4; ++t) {
                        double om = red_s[tid + 64 * t];
                        int    oi = red_i[tid + 64 * t];
                        if (om < m || (om == m && oi < mi)) { m = om; mi = oi; }
                    }
                    #pragma unroll
                    for (int off = 32; off > 0; off >>= 1) {
                        double om = __shfl_down(m, off);
                        int    oi = __shfl_down(mi, off);
                        if (om < m || (om == m && oi < mi)) { m = om; mi = oi; }
                    }
                    if (tid == 0) finidx[p] = mi;
                }
                __syncthreads();
            }
        }
        __syncthreads();
    }

    // ---- epilogue: gather exact fp32 code row -> z_q, loss SSE ----
    // 2 threads per pixel, 32 channels each.
    {
        const int p  = tid & (PPB - 1);
        const int qq = tid >> 7;             // 0..1
        const int fi = finidx[p];
        const float4* crow4 = (const float4*)(cb + (size_t)fi * NC) + qq * 8;
        float sse = 0.f;
        #pragma unroll
        for (int j = 0; j < 8; ++j) {
            const float4 qv = crow4[j];
            const size_t c0 = (size_t)(qq * 32 + 4 * j) * HW + p;
            const float z0 = zbase[c0];
            const float z1 = zbase[c0 + HW];
            const float z2 = zbase[c0 + 2 * (size_t)HW];
            const float z3 = zbase[c0 + 3 * (size_t)HW];
            zqbase[c0]                  = qv.x;   // coalesced across threads
            zqbase[c0 + HW]             = qv.y;
            zqbase[c0 + 2 * (size_t)HW] = qv.z;
            zqbase[c0 + 3 * (size_t)HW] = qv.w;
            float t0 = qv.x - z0, t1 = qv.y - z1, t2 = qv.z - z2, t3 = qv.w - z3;
            sse = fmaf(t0, t0, sse);
            sse = fmaf(t1, t1, sse);
            sse = fmaf(t2, t2, sse);
            sse = fmaf(t3, t3, sse);
        }
        #pragma unroll
        for (int off = 32; off > 0; off >>= 1) sse += __shfl_down(sse, off);
        if ((tid & 63) == 0) redf[tid >> 6] = sse;
        __syncthreads();
        if (tid == 0)
            atomicAdd(loss_out, (redf[0] + redf[1] + redf[2] + redf[3]) *
                                (1.25f / (float)TOTAL));
    }
}

extern "C" void kernel_launch(void* const* d_in, const int* in_sizes, int n_in,
                              void* d_out, int out_size, void* d_ws, size_t ws_size,
                              hipStream_t stream) {
    const float* z  = (const float*)d_in[0];   // [32, 64, 64, 64] fp32
    const float* cb = (const float*)d_in[1];   // [1024, 64] fp32
    float* out      = (float*)d_out;           // z_q ++ loss
    float* zqp      = out;
    float* loss     = out + TOTAL;

    // ws: cnorm fp32[1024] | cb_hi bf16[1024*64] | cb_lo bf16[1024*64]
    float* cnorm          = (float*)d_ws;
    unsigned short* cb_hi = (unsigned short*)((char*)d_ws + 4096);
    unsigned short* cb_lo = (unsigned short*)((char*)d_ws + 4096 + NK * NC * 2);

    vq_prep_kernel<<<16, 64, 0, stream>>>(cb, cnorm, cb_hi, cb_lo, loss);
    vq_mfma_kernel<<<NPIX / PPB, 256, 0, stream>>>(z, cb, cb_hi, cb_lo, cnorm,
                                                   zqp, loss);
}